// Round 10
// baseline (45.004 us; speedup 1.0000x reference)
//
#include <hip/hip_runtime.h>

#define W 512
#define H 512
#define OWID 506
#define OHT 506
#define BC 48              // 16 images * 3 channels
#define SEGOUT 26          // valid output cols per 16-lane segment (2/lane, q<=12)
#define WAVEOUT 104        // 4 segments
#define NSTRIP 5           // 5*104 = 520 >= 506
#define CH 14              // output rows per chunk (2 groups of 7)
#define NCHUNK 37          // 37*14 = 518 >= 506
#define NWAVE (BC*NSTRIP*NCHUNK)   // 8880, divisible by 4
#define NPIX 12289728.0f           // 16*3*506*506

__device__ __forceinline__ float clip01(float v) { return fminf(fmaxf(v, 0.f), 1.f); }

// DPP row_shl:N — lane p receives lane p+N within its 16-lane row; 0 if OOB.
template <int N>
__device__ __forceinline__ float dpp_shl(float v) {
    int r = __builtin_amdgcn_update_dpp(0, __float_as_int(v),
                                        0x100 + N, 0xF, 0xF, true);
    return __int_as_float(r);
}

// V = (even-col sum, odd-col sum). Returns (h for col 2q, h for col 2q+1).
// P=Ve+Vo; S4 = 8-col sum (lanes q..q+3); h_e = S4 - col(2q+7); h_o = S4 - col(2q).
__device__ __forceinline__ float2 hpair(float2 V) {
    float P  = V.x + V.y;
    float S2 = P + dpp_shl<1>(P);
    float S4 = S2 + dpp_shl<2>(S2);
    float2 h;
    h.x = S4 - dpp_shl<3>(V.y);
    h.y = S4 - V.x;
    return h;
}

// sum-domain SSIM (scaled by 49^4)
__device__ __forceinline__ float ssim_v(float a0, float a1, float az, float a4) {
    const float c1p   = 0.2401f;        // C1 * 49^2
    const float c2p   = 2.1609f;        // C2 * 49^2
    const float covn  = 49.0f / 48.0f;
    const float covn2 = 49.0f / 24.0f;
    float t01  = a0 * a1;
    float qs   = fmaf(a0, a0, a1 * a1);
    float w4   = fmaf(49.f, a4, -t01);
    float num1 = fmaf(2.f, t01, c1p);
    float num2 = fmaf(covn2, w4, c2p);
    float w23  = fmaf(49.f, az, -qs);
    float den1 = qs + c1p;
    float den2 = fmaf(covn, w23, c2p);
    return (num1 * num2) * __builtin_amdgcn_rcpf(den1 * den2);
}

__global__ __launch_bounds__(256)
void ssim_stream(const float* __restrict__ pred, const float* __restrict__ targ,
                 float* __restrict__ partial, float* __restrict__ out_atomic)
{
    // wave-uniform id -> SGPR addressing, scalar row pointers
    const int wid  = __builtin_amdgcn_readfirstlane(blockIdx.x * 4 + (threadIdx.x >> 6));
    const int lane = threadIdx.x & 63;
    const int seg  = lane >> 4;
    const int q    = lane & 15;

    const int bc    = wid / (NSTRIP * NCHUNK);
    const int rem   = wid - bc * (NSTRIP * NCHUNK);
    const int strip = rem / NCHUNK;
    const int chunk = rem - strip * NCHUNK;

    const int ce = strip * WAVEOUT + seg * SEGOUT + 2 * q;  // even col this lane owns
    const int co = min(ce, W - 2);                          // clamped float2 col
    const bool oke = (q <= 12) && (ce     < OWID);
    const bool oko = (q <= 12) && (ce + 1 < OWID);

    const int oy0 = chunk * CH;
    const size_t base = (size_t)bc * (H * W) + (size_t)oy0 * W;
    const float* __restrict__ px = pred + base;   // scalar base, row oy0
    const float* __restrict__ py = targ + base;

    // ---- init: ring rows 0..6 (direct, loads issue in parallel) ----
    float2 ringx[7], ringy[7];
    float2 Vx = {0,0}, Vy = {0,0}, Vz = {0,0}, Vxy = {0,0};
    #pragma unroll
    for (int i = 0; i < 7; ++i) {                 // rows oy0..oy0+6 <= 510
        float2 xr = *(const float2*)(px + i * W + co);
        float2 yr = *(const float2*)(py + i * W + co);
        float2 x, y;
        x.x = clip01(xr.x); x.y = clip01(xr.y);
        y.x = clip01(yr.x); y.y = clip01(yr.y);
        ringx[i] = x; ringy[i] = y;
        Vx.x += x.x; Vx.y += x.y;
        Vy.x += y.x; Vy.y += y.y;
        Vz.x  = fmaf(x.x, x.x, Vz.x);  Vz.x  = fmaf(y.x, y.x, Vz.x);
        Vz.y  = fmaf(x.y, x.y, Vz.y);  Vz.y  = fmaf(y.y, y.y, Vz.y);
        Vxy.x = fmaf(x.x, y.x, Vxy.x);
        Vxy.y = fmaf(x.y, y.y, Vxy.y);
    }

    // ---- 2-deep prefetch: n1 = row 7, n2 = row 8 (CLAMPED: oy0+8 can be 512) ----
    float2 n1x = *(const float2*)(px + 7 * W + co);          // oy0+7 <= 511
    float2 n1y = *(const float2*)(py + 7 * W + co);
    const int r8 = min(oy0 + 8, H - 1) - oy0;
    float2 n2x = *(const float2*)(px + r8 * W + co);
    float2 n2y = *(const float2*)(py + r8 * W + co);
    // scalar prefetch pointers for row 9+, clamped
    const int r9 = min(oy0 + 9, H - 1) - oy0;
    const float* fx = px + r9 * W;
    const float* fy = py + r9 * W;
    int rabs = oy0 + 9;      // unclamped absolute row fx/fy "want" to point at

    float acc = 0.f;

    #pragma unroll 1
    for (int g = 0; g < 2; ++g) {
        if (oy0 + 7 * g >= OHT) break;     // scalar early-exit (last chunk)
        #pragma unroll
        for (int i = 0; i < 7; ++i) {      // t = 7g+i, ring slot i (static)
            const int t = g * 7 + i;
            // ---- emit output row oy0+t: shared-ladder h-pairs, 2 cols/lane ----
            {
                float2 hx = hpair(Vx);
                float2 hy = hpair(Vy);
                float2 hz = hpair(Vz);
                float2 hw = hpair(Vxy);
                float ve = ssim_v(hx.x, hy.x, hz.x, hw.x);
                float vo = ssim_v(hx.y, hy.y, hz.y, hw.y);
                bool rok = (oy0 + t) < OHT;          // scalar
                acc += (oke && rok) ? ve : 0.f;
                acc += (oko && rok) ? vo : 0.f;
            }
            // ---- advance: consume row t+7 (n1), shift n2->n1, load row t+9 ----
            {
                float2 xo = ringx[i], yo = ringy[i];
                float2 xn, yn;
                xn.x = clip01(n1x.x); xn.y = clip01(n1x.y);
                yn.x = clip01(n1y.x); yn.y = clip01(n1y.y);
                n1x = n2x; n1y = n2y;
                n2x = *(const float2*)(fx + co);
                n2y = *(const float2*)(fy + co);
                if (rabs < H - 1) { fx += W; fy += W; }  // scalar guard
                ++rabs;
                Vx.x += xn.x - xo.x;  Vx.y += xn.y - xo.y;
                Vy.x += yn.x - yo.x;  Vy.y += yn.y - yo.y;
                float zne = fmaf(xn.x, xn.x, yn.x * yn.x);
                float zoe = fmaf(xo.x, xo.x, yo.x * yo.x);
                float zno = fmaf(xn.y, xn.y, yn.y * yn.y);
                float zoo = fmaf(xo.y, xo.y, yo.y * yo.y);
                Vz.x += zne - zoe;    Vz.y += zno - zoo;
                Vxy.x += fmaf(xn.x, yn.x, -(xo.x * yo.x));
                Vxy.y += fmaf(xn.y, yn.y, -(xo.y * yo.y));
                ringx[i] = xn; ringy[i] = yn;
            }
        }
    }

    // ---- wave reduction, one partial per wave ----
    #pragma unroll
    for (int off = 32; off >= 1; off >>= 1)
        acc += __shfl_down(acc, off, 64);
    if (lane == 0) {
        if (partial) partial[wid] = acc;
        else atomicAdd(out_atomic, acc);
    }
}

__global__ __launch_bounds__(256)
void ssim_finish(const float* __restrict__ partial, float* __restrict__ out)
{
    __shared__ float red[4];
    float s = 0.f;
    for (int i = threadIdx.x; i < NWAVE; i += 256) s += partial[i];
    #pragma unroll
    for (int off = 32; off >= 1; off >>= 1)
        s += __shfl_down(s, off, 64);
    if ((threadIdx.x & 63) == 0) red[threadIdx.x >> 6] = s;
    __syncthreads();
    if (threadIdx.x == 0) {
        float t = red[0] + red[1] + red[2] + red[3];
        out[0] = 1.0f - t / NPIX;
    }
}

__global__ void ssim_zero(float* out) { out[0] = 0.0f; }
__global__ void ssim_finish_atomic(float* out) { out[0] = 1.0f - out[0] / NPIX; }

extern "C" void kernel_launch(void* const* d_in, const int* in_sizes, int n_in,
                              void* d_out, int out_size, void* d_ws, size_t ws_size,
                              hipStream_t stream) {
    const float* pred = (const float*)d_in[0];
    const float* targ = (const float*)d_in[1];
    float* out = (float*)d_out;

    dim3 block(256);
    dim3 grid(NWAVE / 4);   // 2220 blocks, 4 waves each

    if (ws_size >= (size_t)NWAVE * sizeof(float)) {
        float* part = (float*)d_ws;
        ssim_stream<<<grid, block, 0, stream>>>(pred, targ, part, nullptr);
        ssim_finish<<<1, 256, 0, stream>>>(part, out);
    } else {
        ssim_zero<<<1, 1, 0, stream>>>(out);
        ssim_stream<<<grid, block, 0, stream>>>(pred, targ, nullptr, out);
        ssim_finish_atomic<<<1, 1, 0, stream>>>(out);
    }
}

// Round 11
// 38.995 us; speedup vs baseline: 1.1541x; 1.1541x over previous
//
#include <hip/hip_runtime.h>

#define W 512
#define H 512
#define OWID 506
#define OHT 506
#define BC 48              // 16 images * 3 channels
#define SEGOUT 26          // valid output cols per 16-lane segment (2/lane, q<=12)
#define WAVEOUT 104        // 4 segments
#define NSTRIP 5           // 5*104 = 520 >= 506
#define CH 28              // output rows per chunk (4 groups of 7)
#define NCHUNK 19          // 19*28 = 532 >= 506
#define NWAVE (BC*NSTRIP*NCHUNK)   // 4560, divisible by 4
#define NPIX 12289728.0f           // 16*3*506*506

__device__ __forceinline__ float clip01(float v) { return fminf(fmaxf(v, 0.f), 1.f); }

// DPP row_shl:N — lane p receives lane p+N within its 16-lane row; 0 if OOB.
template <int N>
__device__ __forceinline__ float dpp_shl(float v) {
    int r = __builtin_amdgcn_update_dpp(0, __float_as_int(v),
                                        0x100 + N, 0xF, 0xF, true);
    return __int_as_float(r);
}

// V = (even-col sum, odd-col sum). Returns (h for col 2q, h for col 2q+1).
// P=Ve+Vo; S4 = 8-col sum (lanes q..q+3); h_e = S4 - col(2q+7); h_o = S4 - col(2q).
__device__ __forceinline__ float2 hpair(float2 V) {
    float P  = V.x + V.y;
    float S2 = P + dpp_shl<1>(P);
    float S4 = S2 + dpp_shl<2>(S2);
    float2 h;
    h.x = S4 - dpp_shl<3>(V.y);
    h.y = S4 - V.x;
    return h;
}

// sum-domain SSIM (scaled by 49^4)
__device__ __forceinline__ float ssim_v(float a0, float a1, float az, float a4) {
    const float c1p   = 0.2401f;        // C1 * 49^2
    const float c2p   = 2.1609f;        // C2 * 49^2
    const float covn  = 49.0f / 48.0f;
    const float covn2 = 49.0f / 24.0f;
    float t01  = a0 * a1;
    float qs   = fmaf(a0, a0, a1 * a1);
    float w4   = fmaf(49.f, a4, -t01);
    float num1 = fmaf(2.f, t01, c1p);
    float num2 = fmaf(covn2, w4, c2p);
    float w23  = fmaf(49.f, az, -qs);
    float den1 = qs + c1p;
    float den2 = fmaf(covn, w23, c2p);
    return (num1 * num2) * __builtin_amdgcn_rcpf(den1 * den2);
}

__global__ __launch_bounds__(256)
void ssim_stream(const float* __restrict__ pred, const float* __restrict__ targ,
                 float* __restrict__ partial, float* __restrict__ out_atomic)
{
    // wave-uniform id -> SGPR addressing, scalar row pointers
    const int wid  = __builtin_amdgcn_readfirstlane(blockIdx.x * 4 + (threadIdx.x >> 6));
    const int lane = threadIdx.x & 63;
    const int seg  = lane >> 4;
    const int q    = lane & 15;

    const int bc    = wid / (NSTRIP * NCHUNK);
    const int rem   = wid - bc * (NSTRIP * NCHUNK);
    const int strip = rem / NCHUNK;
    const int chunk = rem - strip * NCHUNK;

    const int ce = strip * WAVEOUT + seg * SEGOUT + 2 * q;  // even col this lane owns
    const int co = min(ce, W - 2);                          // clamped float2 col
    const bool oke = (q <= 12) && (ce     < OWID);
    const bool oko = (q <= 12) && (ce + 1 < OWID);

    const int oy0 = chunk * CH;
    const size_t base = (size_t)bc * (H * W) + (size_t)oy0 * W;
    const float* __restrict__ px = pred + base;   // scalar base, row oy0
    const float* __restrict__ py = targ + base;

    // ---- depth-7 prefetch ring: 14 loads in flight per wave ----
    float2 pfx[7], pfy[7];
    #pragma unroll
    for (int i = 0; i < 7; ++i) {                 // rows oy0..oy0+6 <= 510
        pfx[i] = *(const float2*)(px + i * W + co);
        pfy[i] = *(const float2*)(py + i * W + co);
    }
    // scalar refill pointer: next row to issue = oy0+7 (<=511); clamp via guard
    const float* fx = px + 7 * W;
    const float* fy = py + 7 * W;
    int rabs = oy0 + 7;     // abs row fx/fy point at (advance only while < H-1)

    // ---- init-consume rows 0..6, refilling ring with rows 7..13 ----
    float2 ringx[7], ringy[7];
    float2 Vx = {0,0}, Vy = {0,0}, Vz = {0,0}, Vxy = {0,0};
    #pragma unroll
    for (int i = 0; i < 7; ++i) {
        float2 xr = pfx[i], yr = pfy[i];          // waits oldest loads only
        pfx[i] = *(const float2*)(fx + co);       // refill: row oy0+7+i (clamped)
        pfy[i] = *(const float2*)(fy + co);
        if (rabs < H - 1) { fx += W; fy += W; }   // scalar guard
        ++rabs;
        float2 x, y;
        x.x = clip01(xr.x); x.y = clip01(xr.y);
        y.x = clip01(yr.x); y.y = clip01(yr.y);
        ringx[i] = x; ringy[i] = y;
        Vx.x += x.x; Vx.y += x.y;
        Vy.x += y.x; Vy.y += y.y;
        Vz.x  = fmaf(x.x, x.x, Vz.x);  Vz.x  = fmaf(y.x, y.x, Vz.x);
        Vz.y  = fmaf(x.y, x.y, Vz.y);  Vz.y  = fmaf(y.y, y.y, Vz.y);
        Vxy.x = fmaf(x.x, y.x, Vxy.x);
        Vxy.y = fmaf(x.y, y.y, Vxy.y);
    }

    float acc = 0.f;

    #pragma unroll 1
    for (int g = 0; g < 4; ++g) {
        if (oy0 + 7 * g >= OHT) break;     // scalar early-exit (last chunk)
        #pragma unroll
        for (int i = 0; i < 7; ++i) {      // t = 7g+i; ring slot i (compile-time)
            const int t = g * 7 + i;
            // ---- emit output row oy0+t: shared-ladder h-pairs, 2 cols/lane ----
            {
                float2 hx = hpair(Vx);
                float2 hy = hpair(Vy);
                float2 hz = hpair(Vz);
                float2 hw = hpair(Vxy);
                float ve = ssim_v(hx.x, hy.x, hz.x, hw.x);
                float vo = ssim_v(hx.y, hy.y, hz.y, hw.y);
                bool rok = (oy0 + t) < OHT;          // scalar
                acc += (oke && rok) ? ve : 0.f;
                acc += (oko && rok) ? vo : 0.f;
            }
            // ---- advance: consume row t+7 from slot i, refill row t+14 ----
            {
                float2 xo = ringx[i], yo = ringy[i];
                float2 xr = pfx[i], yr = pfy[i];     // row t+7 (issued 7 iters ago)
                pfx[i] = *(const float2*)(fx + co);  // issue row t+14 (clamped)
                pfy[i] = *(const float2*)(fy + co);
                if (rabs < H - 1) { fx += W; fy += W; }  // scalar guard
                ++rabs;
                float2 xn, yn;
                xn.x = clip01(xr.x); xn.y = clip01(xr.y);
                yn.x = clip01(yr.x); yn.y = clip01(yr.y);
                Vx.x += xn.x - xo.x;  Vx.y += xn.y - xo.y;
                Vy.x += yn.x - yo.x;  Vy.y += yn.y - yo.y;
                float zne = fmaf(xn.x, xn.x, yn.x * yn.x);
                float zoe = fmaf(xo.x, xo.x, yo.x * yo.x);
                float zno = fmaf(xn.y, xn.y, yn.y * yn.y);
                float zoo = fmaf(xo.y, xo.y, yo.y * yo.y);
                Vz.x += zne - zoe;    Vz.y += zno - zoo;
                Vxy.x += fmaf(xn.x, yn.x, -(xo.x * yo.x));
                Vxy.y += fmaf(xn.y, yn.y, -(xo.y * yo.y));
                ringx[i] = xn; ringy[i] = yn;
            }
        }
    }

    // ---- wave reduction, one partial per wave ----
    #pragma unroll
    for (int off = 32; off >= 1; off >>= 1)
        acc += __shfl_down(acc, off, 64);
    if (lane == 0) {
        if (partial) partial[wid] = acc;
        else atomicAdd(out_atomic, acc);
    }
}

__global__ __launch_bounds__(256)
void ssim_finish(const float* __restrict__ partial, float* __restrict__ out)
{
    __shared__ float red[4];
    float s = 0.f;
    for (int i = threadIdx.x; i < NWAVE; i += 256) s += partial[i];
    #pragma unroll
    for (int off = 32; off >= 1; off >>= 1)
        s += __shfl_down(s, off, 64);
    if ((threadIdx.x & 63) == 0) red[threadIdx.x >> 6] = s;
    __syncthreads();
    if (threadIdx.x == 0) {
        float t = red[0] + red[1] + red[2] + red[3];
        out[0] = 1.0f - t / NPIX;
    }
}

__global__ void ssim_zero(float* out) { out[0] = 0.0f; }
__global__ void ssim_finish_atomic(float* out) { out[0] = 1.0f - out[0] / NPIX; }

extern "C" void kernel_launch(void* const* d_in, const int* in_sizes, int n_in,
                              void* d_out, int out_size, void* d_ws, size_t ws_size,
                              hipStream_t stream) {
    const float* pred = (const float*)d_in[0];
    const float* targ = (const float*)d_in[1];
    float* out = (float*)d_out;

    dim3 block(256);
    dim3 grid(NWAVE / 4);   // 1140 blocks, 4 waves each

    if (ws_size >= (size_t)NWAVE * sizeof(float)) {
        float* part = (float*)d_ws;
        ssim_stream<<<grid, block, 0, stream>>>(pred, targ, part, nullptr);
        ssim_finish<<<1, 256, 0, stream>>>(part, out);
    } else {
        ssim_zero<<<1, 1, 0, stream>>>(out);
        ssim_stream<<<grid, block, 0, stream>>>(pred, targ, nullptr, out);
        ssim_finish_atomic<<<1, 1, 0, stream>>>(out);
    }
}